// Round 1
// baseline (17.526 us; speedup 1.0000x reference)
//
#include <hip/hip_runtime.h>

// DCN cross layer, B x D f32, D = 1024, LAYERS = 3.
// x_{l+1} = x0 * (x_l . w_l) + b_l + x_l
//
// One wave (64 lanes) per row: 64 lanes x 16 floats (4x float4) = 1024 = D.
// x0 and x_l live in registers; per-layer scalar dot via wave-64 shfl_xor
// butterfly; W[i]/b[i] are 4 KB each and L1-resident after the first block.
// Memory-bound: ideal traffic = 32 MiB read + 32 MiB write.

#define DDIM 1024
#define LAYERS 3

__global__ __launch_bounds__(256) void CrossLayer_kernel(
    const float* __restrict__ x,
    const float* __restrict__ W,
    const float* __restrict__ bias,
    float* __restrict__ out,
    int B)
{
    const int wave = threadIdx.x >> 6;   // 0..3, one row per wave
    const int lane = threadIdx.x & 63;
    const int row  = blockIdx.x * 4 + wave;
    if (row >= B) return;

    const float4* xrow = reinterpret_cast<const float4*>(x + (size_t)row * DDIM);

    float4 x0[4], xl[4];
#pragma unroll
    for (int c = 0; c < 4; ++c) {
        x0[c] = xrow[c * 64 + lane];     // elem offset c*256 + lane*4, coalesced
        xl[c] = x0[c];
    }

#pragma unroll
    for (int l = 0; l < LAYERS; ++l) {
        const float4* wrow = reinterpret_cast<const float4*>(W    + l * DDIM);
        const float4* brow = reinterpret_cast<const float4*>(bias + l * DDIM);

        // per-lane partial of (x_l . w_l)
        float partial = 0.f;
#pragma unroll
        for (int c = 0; c < 4; ++c) {
            float4 w = wrow[c * 64 + lane];
            partial += xl[c].x * w.x + xl[c].y * w.y
                     + xl[c].z * w.z + xl[c].w * w.w;
        }
        // wave-64 butterfly reduction (all lanes end with the full sum)
#pragma unroll
        for (int off = 32; off > 0; off >>= 1)
            partial += __shfl_xor(partial, off, 64);
        const float scale = partial;

        // x_l = x0 * scale + b + x_l
#pragma unroll
        for (int c = 0; c < 4; ++c) {
            float4 bv = brow[c * 64 + lane];
            xl[c].x = fmaf(x0[c].x, scale, bv.x + xl[c].x);
            xl[c].y = fmaf(x0[c].y, scale, bv.y + xl[c].y);
            xl[c].z = fmaf(x0[c].z, scale, bv.z + xl[c].z);
            xl[c].w = fmaf(x0[c].w, scale, bv.w + xl[c].w);
        }
    }

    float4* orow = reinterpret_cast<float4*>(out + (size_t)row * DDIM);
#pragma unroll
    for (int c = 0; c < 4; ++c)
        orow[c * 64 + lane] = xl[c];
}

extern "C" void kernel_launch(void* const* d_in, const int* in_sizes, int n_in,
                              void* d_out, int out_size, void* d_ws, size_t ws_size,
                              hipStream_t stream) {
    const float* x  = (const float*)d_in[0];
    const float* W  = (const float*)d_in[1];
    const float* b  = (const float*)d_in[2];
    float* out      = (float*)d_out;

    const int B = in_sizes[0] / DDIM;          // 8192
    dim3 grid((B + 3) / 4), block(256);
    hipLaunchKernelGGL(CrossLayer_kernel, grid, block, 0, stream,
                       x, W, b, out, B);
}

// Round 3
// 17.082 us; speedup vs baseline: 1.0260x; 1.0260x over previous
//
#include <hip/hip_runtime.h>

// DCN cross layer, B x D f32, D = 1024, LAYERS = 3.
// x_{l+1} = x0 * (x_l . w_l) + b_l + x_l
//
// Algebraic closed form (removes the serial 3-layer chain):
//   d_i  = x0 . W_i            (3 row-dependent dots, one pass over x)
//   c1   = b0 . W1,  c2 = (b0+b1) . W2      (row-independent, W/b are L1-hot)
//   s0 = d0
//   s1 = (1+s0) d1 + c1
//   s2 = (1+s0+s1) d2 + c2
//   out = x0 * (1+s0+s1+s2) + (b0+b1+b2)
//
// One wave per row (64 lanes x 4 float4 = 1024 = D). Single butterfly
// reduction round over 5 independent partials (ILP-overlapped), then one
// FMA + nontemporal streaming store. Memory-bound: 32 MiB in + 32 MiB out.

#define DDIM 1024
#define LAYERS 3

typedef float f32x4 __attribute__((ext_vector_type(4)));

__global__ __launch_bounds__(256) void CrossLayer_kernel(
    const float* __restrict__ x,
    const float* __restrict__ W,
    const float* __restrict__ bias,
    float* __restrict__ out,
    int B)
{
    const int wave = threadIdx.x >> 6;   // 0..3, one row per wave
    const int lane = threadIdx.x & 63;
    const int row  = blockIdx.x * 4 + wave;
    if (row >= B) return;

    const f32x4* xrow = reinterpret_cast<const f32x4*>(x + (size_t)row * DDIM);
    const f32x4* w0   = reinterpret_cast<const f32x4*>(W);
    const f32x4* w1   = reinterpret_cast<const f32x4*>(W + DDIM);
    const f32x4* w2   = reinterpret_cast<const f32x4*>(W + 2 * DDIM);
    const f32x4* b0   = reinterpret_cast<const f32x4*>(bias);
    const f32x4* b1   = reinterpret_cast<const f32x4*>(bias + DDIM);
    const f32x4* b2   = reinterpret_cast<const f32x4*>(bias + 2 * DDIM);

    f32x4 x0[4];
    float d0 = 0.f, d1 = 0.f, d2 = 0.f;   // x0 . W_i partials
    float c1 = 0.f, c2 = 0.f;             // b0.W1, (b0+b1).W2 partials

#pragma unroll
    for (int c = 0; c < 4; ++c) {
        const int idx = c * 64 + lane;
        f32x4 xv = xrow[idx];
        x0[c] = xv;
        f32x4 wv0 = w0[idx], wv1 = w1[idx], wv2 = w2[idx];
        f32x4 bv0 = b0[idx], bv1 = b1[idx];

        d0 += xv.x * wv0.x + xv.y * wv0.y + xv.z * wv0.z + xv.w * wv0.w;
        d1 += xv.x * wv1.x + xv.y * wv1.y + xv.z * wv1.z + xv.w * wv1.w;
        d2 += xv.x * wv2.x + xv.y * wv2.y + xv.z * wv2.z + xv.w * wv2.w;

        c1 += bv0.x * wv1.x + bv0.y * wv1.y + bv0.z * wv1.z + bv0.w * wv1.w;
        f32x4 b01 = bv0 + bv1;
        c2 += b01.x * wv2.x + b01.y * wv2.y + b01.z * wv2.z + b01.w * wv2.w;
    }

    // one butterfly round, 5 independent values (shfls overlap)
#pragma unroll
    for (int off = 32; off > 0; off >>= 1) {
        d0 += __shfl_xor(d0, off, 64);
        d1 += __shfl_xor(d1, off, 64);
        d2 += __shfl_xor(d2, off, 64);
        c1 += __shfl_xor(c1, off, 64);
        c2 += __shfl_xor(c2, off, 64);
    }

    // scalar recurrence
    const float s0 = d0;
    const float t1 = 1.f + s0;
    const float s1 = fmaf(t1, d1, c1);
    const float t2 = t1 + s1;
    const float s2 = fmaf(t2, d2, c2);
    const float alpha = t2 + s2;

    f32x4* orow = reinterpret_cast<f32x4*>(out + (size_t)row * DDIM);
#pragma unroll
    for (int c = 0; c < 4; ++c) {
        const int idx = c * 64 + lane;
        f32x4 bv0 = b0[idx], bv1 = b1[idx], bv2 = b2[idx];
        f32x4 bsum = bv0 + bv1 + bv2;
        f32x4 o;
        o.x = fmaf(x0[c].x, alpha, bsum.x);
        o.y = fmaf(x0[c].y, alpha, bsum.y);
        o.z = fmaf(x0[c].z, alpha, bsum.z);
        o.w = fmaf(x0[c].w, alpha, bsum.w);
        __builtin_nontemporal_store(o, &orow[idx]);
    }
}

extern "C" void kernel_launch(void* const* d_in, const int* in_sizes, int n_in,
                              void* d_out, int out_size, void* d_ws, size_t ws_size,
                              hipStream_t stream) {
    const float* x  = (const float*)d_in[0];
    const float* W  = (const float*)d_in[1];
    const float* b  = (const float*)d_in[2];
    float* out      = (float*)d_out;

    const int B = in_sizes[0] / DDIM;          // 8192
    dim3 grid((B + 3) / 4), block(256);
    hipLaunchKernelGGL(CrossLayer_kernel, grid, block, 0, stream,
                       x, W, b, out, B);
}

// Round 4
// 14.108 us; speedup vs baseline: 1.2423x; 1.2108x over previous
//
#include <hip/hip_runtime.h>

// DCN cross layer, B x D f32, D = 1024, LAYERS = 3.
// x_{l+1} = x0 * (x_l . w_l) + b_l + x_l
//
// Closed form:
//   d_i = x0 . W_i;  c1 = b0.W1;  c2 = (b0+b1).W2
//   s0 = d0; s1 = (1+s0)d1 + c1; s2 = (1+s0+s1)d2 + c2
//   out = x0*(1+s0+s1+s2) + (b0+b1+b2)
//
// R4: 4 rows per wave. All 16 HBM x-loads issued up front (max MLP);
// W/b read once per wave (L1-hot) and amortized over 4 rows; bsum kept
// in registers for the epilogue. 10 VMEM loads/row vs 36 in R3.

#define DDIM 1024
#define RPW 4

typedef float f32x4 __attribute__((ext_vector_type(4)));

__device__ __forceinline__ float dot4(f32x4 a, f32x4 b) {
    return fmaf(a.x, b.x, fmaf(a.y, b.y, fmaf(a.z, b.z, a.w * b.w)));
}

__global__ __launch_bounds__(256) void CrossLayer_kernel(
    const float* __restrict__ x,
    const float* __restrict__ W,
    const float* __restrict__ bias,
    float* __restrict__ out,
    int B)
{
    const int wave = threadIdx.x >> 6;
    const int lane = threadIdx.x & 63;
    const int wid  = blockIdx.x * 4 + wave;
    const int row0 = wid * RPW;
    if (row0 >= B) return;

    const f32x4* w0 = reinterpret_cast<const f32x4*>(W);
    const f32x4* w1 = reinterpret_cast<const f32x4*>(W + DDIM);
    const f32x4* w2 = reinterpret_cast<const f32x4*>(W + 2 * DDIM);
    const f32x4* b0 = reinterpret_cast<const f32x4*>(bias);
    const f32x4* b1 = reinterpret_cast<const f32x4*>(bias + DDIM);
    const f32x4* b2 = reinterpret_cast<const f32x4*>(bias + 2 * DDIM);

    // ---- issue all HBM loads first (16 dwordx4 in flight) ----
    f32x4 x0[RPW][4];
#pragma unroll
    for (int r = 0; r < RPW; ++r) {
        const f32x4* xr = reinterpret_cast<const f32x4*>(x + (size_t)(row0 + r) * DDIM);
#pragma unroll
        for (int c = 0; c < 4; ++c)
            x0[r][c] = xr[c * 64 + lane];
    }

    // ---- W/b pass (L1-hot), amortized over RPW rows ----
    f32x4 bsum[4];
    float d[RPW][3];
#pragma unroll
    for (int r = 0; r < RPW; ++r) { d[r][0] = d[r][1] = d[r][2] = 0.f; }
    float c1 = 0.f, c2 = 0.f;

#pragma unroll
    for (int c = 0; c < 4; ++c) {
        const int idx = c * 64 + lane;
        f32x4 wv0 = w0[idx], wv1 = w1[idx], wv2 = w2[idx];
        f32x4 bv0 = b0[idx], bv1 = b1[idx], bv2 = b2[idx];
        bsum[c] = bv0 + bv1 + bv2;
        c1 += dot4(bv0, wv1);
        f32x4 b01 = bv0 + bv1;
        c2 += dot4(b01, wv2);
#pragma unroll
        for (int r = 0; r < RPW; ++r) {
            d[r][0] += dot4(x0[r][c], wv0);
            d[r][1] += dot4(x0[r][c], wv1);
            d[r][2] += dot4(x0[r][c], wv2);
        }
    }

    // ---- one butterfly round over 14 independent values ----
#pragma unroll
    for (int off = 32; off > 0; off >>= 1) {
        c1 += __shfl_xor(c1, off, 64);
        c2 += __shfl_xor(c2, off, 64);
#pragma unroll
        for (int r = 0; r < RPW; ++r) {
            d[r][0] += __shfl_xor(d[r][0], off, 64);
            d[r][1] += __shfl_xor(d[r][1], off, 64);
            d[r][2] += __shfl_xor(d[r][2], off, 64);
        }
    }

    // ---- scalar recurrences ----
    float alpha[RPW];
#pragma unroll
    for (int r = 0; r < RPW; ++r) {
        const float t1 = 1.f + d[r][0];
        const float s1 = fmaf(t1, d[r][1], c1);
        const float t2 = t1 + s1;
        const float s2 = fmaf(t2, d[r][2], c2);
        alpha[r] = t2 + s2;
    }

    // ---- epilogue: out = x0*alpha + bsum, streaming stores ----
#pragma unroll
    for (int r = 0; r < RPW; ++r) {
        f32x4* orow = reinterpret_cast<f32x4*>(out + (size_t)(row0 + r) * DDIM);
#pragma unroll
        for (int c = 0; c < 4; ++c) {
            f32x4 o;
            o.x = fmaf(x0[r][c].x, alpha[r], bsum[c].x);
            o.y = fmaf(x0[r][c].y, alpha[r], bsum[c].y);
            o.z = fmaf(x0[r][c].z, alpha[r], bsum[c].z);
            o.w = fmaf(x0[r][c].w, alpha[r], bsum[c].w);
            __builtin_nontemporal_store(o, &orow[c * 64 + lane]);
        }
    }
}

extern "C" void kernel_launch(void* const* d_in, const int* in_sizes, int n_in,
                              void* d_out, int out_size, void* d_ws, size_t ws_size,
                              hipStream_t stream) {
    const float* x  = (const float*)d_in[0];
    const float* W  = (const float*)d_in[1];
    const float* b  = (const float*)d_in[2];
    float* out      = (float*)d_out;

    const int B = in_sizes[0] / DDIM;              // 8192
    const int rows_per_block = 4 * RPW;            // 16
    dim3 grid((B + rows_per_block - 1) / rows_per_block), block(256);
    hipLaunchKernelGGL(CrossLayer_kernel, grid, block, 0, stream,
                       x, W, b, out, B);
}